// Round 1
// baseline (1201.042 us; speedup 1.0000x reference)
//
#include <hip/hip_runtime.h>

// RNNCell scan: T=512, B=16384, H=32.
// 4 batch elems per wave (one per DPP row of 16); lane l owns h/j = {l, l+16}.
// W2 register-resident, pre-permuted in XOR order; activation broadcast via
// DPP xor ctrls (quad_perm / half_mirror / mirror / ror:8) on the VALU pipe.

#define T_STEPS 512
#define B_TOT   16384

template <int CTRL, int BC>
__device__ __forceinline__ float dppf(float x) {
    return __int_as_float(
        __builtin_amdgcn_update_dpp(0, __float_as_int(x), CTRL, 0xF, 0xF, BC));
}

// softplus(z) and sigmoid(z), sharing exp(-|z|)
__device__ __forceinline__ void sp_sig(float z, float& sp, float& sg) {
    const float az = fabsf(z);
    const float e  = __builtin_amdgcn_exp2f(az * -1.44269504088896340736f); // exp(-|z|)
    const float op = 1.0f + e;
    const float r  = __builtin_amdgcn_rcpf(op);        // 1/(1+e) = sigmoid(|z|)
    const float lg = __builtin_amdgcn_logf(op);        // log2(1+e)
    sp = fmaxf(z, 0.0f) + 0.69314718055994530942f * lg;
    sg = (z >= 0.0f) ? r : e * r;
}

__device__ __forceinline__ float sigm(float z) {
    const float az = fabsf(z);
    const float e  = __builtin_amdgcn_exp2f(az * -1.44269504088896340736f);
    const float r  = __builtin_amdgcn_rcpf(1.0f + e);
    return (z >= 0.0f) ? r : e * r;
}

// ---- matvec over 16 lanes x 2 h per lane, XOR-ordered weights ----
// step s: lane l sees activation of lane l^s; weight regs [2s],[2s+1].
#define MV_STEP_P(gl, gh, S_, WA, WB)                         \
    t0a = fmaf((gl), WA[2*(S_)],     t0a);                    \
    t0b = fmaf((gh), WA[2*(S_) + 1], t0b);                    \
    t1a = fmaf((gl), WB[2*(S_)],     t1a);                    \
    t1b = fmaf((gh), WB[2*(S_) + 1], t1b);

#define MV_STEP_D(gl, gh, S_, CTRL, WA, WB)                   \
    t0a = fmaf(dppf<CTRL, 0>(gl), WA[2*(S_)],     t0a);       \
    t0b = fmaf(dppf<CTRL, 0>(gh), WA[2*(S_) + 1], t0b);       \
    t1a = fmaf(dppf<CTRL, 1>(gl), WB[2*(S_)],     t1a);       \
    t1b = fmaf(dppf<CTRL, 1>(gh), WB[2*(S_) + 1], t1b);

#define MV_GROUP(gl, gh, B_, WA, WB)                          \
    MV_STEP_P(gl, gh, (B_),     WA, WB)                       \
    MV_STEP_D(gl, gh, (B_) ^ 1, 0xB1, WA, WB)                 \
    MV_STEP_D(gl, gh, (B_) ^ 2, 0x4E, WA, WB)                 \
    MV_STEP_D(gl, gh, (B_) ^ 3, 0x1B, WA, WB)

#define MV_ALL(vlo, vhi, WA, WB, OUT0, OUT1, BIAS0, BIAS1)    \
    do {                                                      \
        float t0a = 0.f, t0b = 0.f, t1a = 0.f, t1b = 0.f;     \
        MV_GROUP((vlo), (vhi), 0, WA, WB)                     \
        {                                                     \
            float glo = dppf<0x128, 0>(vlo);                  \
            float ghi = dppf<0x128, 1>(vhi);                  \
            MV_GROUP(glo, ghi, 8, WA, WB)                     \
        }                                                     \
        {                                                     \
            float glo = dppf<0x141, 0>(vlo);                  \
            float ghi = dppf<0x141, 1>(vhi);                  \
            MV_GROUP(glo, ghi, 7, WA, WB)                     \
        }                                                     \
        {                                                     \
            float glo = dppf<0x140, 0>(vlo);                  \
            float ghi = dppf<0x140, 1>(vhi);                  \
            MV_GROUP(glo, ghi, 15, WA, WB)                    \
        }                                                     \
        (OUT0) = (BIAS0) + (t0a + t0b);                       \
        (OUT1) = (BIAS1) + (t1a + t1b);                       \
    } while (0)

__global__ __launch_bounds__(256, 2) void rnn_scan(
    const float* __restrict__ eps, const float* __restrict__ hs,
    const float* __restrict__ W1,  const float* __restrict__ b1,
    const float* __restrict__ W2,  const float* __restrict__ b2,
    const float* __restrict__ W3,  float* __restrict__ out)
{
    const int lane = threadIdx.x & 63;
    const int wv   = threadIdx.x >> 6;
    const int l    = lane & 15;                       // lane within 16-row
    const int b    = (blockIdx.x << 4) + (wv << 2) + (lane >> 4);

    // per-lane small weights (W1 is (2,32) row-major; W3 is (32,1))
    const float w10a = W1[l],      w10b = W1[16 + l];
    const float w11a = W1[32 + l], w11b = W1[48 + l];
    const float b1a = b1[l], b1b = b1[l + 16];
    const float b2a = b2[l], b2b = b2[l + 16];
    const float w3a = W3[l], w3b = W3[l + 16];

    // W2 (32x32 row-major): columns {l, l+16} and rows {l, l+16}, XOR-ordered
    float cA[32], cB[32], rA[32], rB[32];
#pragma unroll
    for (int s = 0; s < 16; ++s) {
        const int h = l ^ s;
        cA[2*s]     = W2[h * 32 + l];
        cA[2*s + 1] = W2[(h + 16) * 32 + l];
        cB[2*s]     = W2[h * 32 + l + 16];
        cB[2*s + 1] = W2[(h + 16) * 32 + l + 16];
        rA[2*s]     = W2[l * 32 + h];
        rA[2*s + 1] = W2[l * 32 + h + 16];
        rB[2*s]     = W2[(l + 16) * 32 + h];
        rB[2*s + 1] = W2[(l + 16) * 32 + h + 16];
    }

    const float* pe = eps + b;
    const float* ph = hs + b;
    float*       po = out + b;

    float gamma = 0.0f;
    float e_cur = pe[0];
    float h_cur = ph[0];

    for (int t = 0; t < T_STEPS; ++t) {
        const int tn = (t < T_STEPS - 1) ? t + 1 : T_STEPS - 1;
        const float e_nxt = pe[tn * B_TOT];           // prefetch next step
        const float h_nxt = ph[tn * B_TOT];

        // z1 = [eps, gamma] @ W1 + b1 ; a1 = softplus(z1) ; g1 = sigmoid(z1)
        const float z1a = fmaf(e_cur, w10a, fmaf(gamma, w11a, b1a));
        const float z1b = fmaf(e_cur, w10b, fmaf(gamma, w11b, b1b));
        float a1lo, a1hi, g1a, g1b;
        sp_sig(z1a, a1lo, g1a);
        sp_sig(z1b, a1hi, g1b);

        // z2 = a1 @ W2 + b2
        float z2a, z2b;
        MV_ALL(a1lo, a1hi, cA, cB, z2a, z2b, b2a, b2b);

        // v2 = sigmoid(z2) * W3[:,0]
        const float v2lo = sigm(z2a) * w3a;
        const float v2hi = sigm(z2b) * w3b;

        // s1 = v2 @ W2^T
        float slo, shi;
        MV_ALL(v2lo, v2hi, rA, rB, slo, shi, 0.0f, 0.0f);

        // v1 = sigmoid(z1) * s1 ; g = v1 @ W1^T
        const float v1lo = g1a * slo;
        const float v1hi = g1b * shi;
        float p0 = fmaf(v1lo, w10a, v1hi * w10b);     // dx/deps partial
        float p1 = fmaf(v1lo, w11a, v1hi * w11b);     // dx/dgamma partial

        // butterfly sum over the 16-lane row (mask basis {1,2,7,8})
        p0 += dppf<0xB1,  0>(p0);  p1 += dppf<0xB1,  1>(p1);
        p0 += dppf<0x4E,  0>(p0);  p1 += dppf<0x4E,  1>(p1);
        p0 += dppf<0x141, 0>(p0);  p1 += dppf<0x141, 1>(p1);
        p0 += dppf<0x128, 0>(p0);  p1 += dppf<0x128, 1>(p1);

        po[t * B_TOT] = p0;                           // all 16 lanes: same addr/data
        gamma = fmaf(h_cur, -p1, gamma);
        e_cur = e_nxt;
        h_cur = h_nxt;
    }
}

extern "C" void kernel_launch(void* const* d_in, const int* in_sizes, int n_in,
                              void* d_out, int out_size, void* d_ws, size_t ws_size,
                              hipStream_t stream) {
    const float* eps = (const float*)d_in[0];
    const float* hs  = (const float*)d_in[1];
    const float* W1  = (const float*)d_in[2];
    const float* b1  = (const float*)d_in[3];
    const float* W2  = (const float*)d_in[4];
    const float* b2  = (const float*)d_in[5];
    const float* W3  = (const float*)d_in[6];
    float* out = (float*)d_out;

    // 16 batch elems per 256-thread block (4 waves x 4 rows) -> 1024 blocks
    dim3 grid(B_TOT / 16), block(256);
    hipLaunchKernelGGL(rnn_scan, grid, block, 0, stream,
                       eps, hs, W1, b1, W2, b2, W3, out);
}

// Round 3
// 600.540 us; speedup vs baseline: 1.9999x; 1.9999x over previous
//
#include <hip/hip_runtime.h>

// RNNCell scan: T=512, B=16384, H=32.
// 16 batches per wave; the two 32x32 matvecs run on the MFMA pipe as
// transposed GEMMs (batch = D-column = lane&15) with bf16 hi/lo split
// (4 MFMAs per tile) for fp32-quality results. a1/v2 h-axis re-layout via
// padded intra-wave LDS round-trip; final reduction via ds_bpermute.

#define T_STEPS 512
#define B_TOT   16384

typedef __attribute__((ext_vector_type(8))) short short8;
typedef __attribute__((ext_vector_type(4))) float f32x4;
typedef __attribute__((ext_vector_type(4))) int   i32x4;

__device__ __forceinline__ short8 as_s8(i32x4 v) {
    union { i32x4 i; short8 s; } u; u.i = v; return u.s;
}

// softplus(z) and sigmoid(z), sharing exp(-|z|)
__device__ __forceinline__ void sp_sig(float z, float& sp, float& sg) {
    const float az = fabsf(z);
    const float e  = __builtin_amdgcn_exp2f(az * -1.44269504088896340736f);
    const float op = 1.0f + e;
    const float r  = __builtin_amdgcn_rcpf(op);
    const float lg = __builtin_amdgcn_logf(op);        // log2(1+e)
    sp = fmaxf(z, 0.0f) + 0.69314718055994530942f * lg;
    sg = (z >= 0.0f) ? r : e * r;
}

__device__ __forceinline__ float sigm(float z) {
    const float az = fabsf(z);
    const float e  = __builtin_amdgcn_exp2f(az * -1.44269504088896340736f);
    const float r  = __builtin_amdgcn_rcpf(1.0f + e);
    return (z >= 0.0f) ? r : e * r;
}

// split (x0,x1) into packed bf16 hi-pair + lo-pair (lo = exact residual of hi)
__device__ __forceinline__ void sp2(float x0, float x1, int& hi, int& lo) {
    unsigned u0 = __float_as_uint(x0), u1 = __float_as_uint(x1);
    unsigned r0 = (u0 + 0x8000u) & 0xffff0000u;
    unsigned r1 = (u1 + 0x8000u) & 0xffff0000u;
    hi = (int)(r1 | (r0 >> 16));
    float l0 = x0 - __uint_as_float(r0);
    float l1 = x1 - __uint_as_float(r1);
    lo = (int)((__float_as_uint(l1) & 0xffff0000u) | (__float_as_uint(l0) >> 16));
}

#define MFMA(A, B, C) __builtin_amdgcn_mfma_f32_16x16x32_bf16((A), (B), (C), 0, 0, 0)

__global__ __launch_bounds__(256, 1) void rnn_scan(
    const float* __restrict__ eps, const float* __restrict__ hs,
    const float* __restrict__ W1,  const float* __restrict__ b1,
    const float* __restrict__ W2,  const float* __restrict__ b2,
    const float* __restrict__ W3,  float* __restrict__ out)
{
    // per-wave LDS: 2 planes (hi/lo) x 16 h-pairs x (16+1 pad) dwords = 544
    __shared__ int lds[4 * 544];

    const int lane = threadIdx.x & 63;
    const int wv   = threadIdx.x >> 6;
    const int c    = lane & 15;          // batch column
    const int q    = lane >> 4;          // quad index
    const int bidx = blockIdx.x * 64 + wv * 16 + c;

    // D-set h's for this lane: hD[i] = (i<4) ? 4q+i : 16+4q+(i-4)
    float W1e[8], W1g[8], b1D[8], b2D[8], W3D[8];
#pragma unroll
    for (int i = 0; i < 8; ++i) {
        const int h = (i < 4) ? (4 * q + i) : (12 + 4 * q + i);
        W1e[i] = W1[h];       // W1[0][h]
        W1g[i] = W1[32 + h];  // W1[1][h]
        b1D[i] = b1[h];
        b2D[i] = b2[h];
        W3D[i] = W3[h];
    }

    // A fragments (wave-uniform weights), hi/lo bf16 split.
    // GEMM1: z2^T = W2^T @ a1^T : A1[tile][m=c][k=8q+j] = W2[8q+j][16*tile+c]
    // GEMM2: s1^T = W2  @ v2^T : A2[tile][m=c][k=8q+j] = W2[16*tile+c][8q+j]
    i32x4 A1h[2], A1l[2], A2h[2], A2l[2];
#pragma unroll
    for (int tile = 0; tile < 2; ++tile) {
#pragma unroll
        for (int p = 0; p < 4; ++p) {
            int th, tl;
            const float x0 = W2[(8 * q + 2 * p) * 32 + 16 * tile + c];
            const float x1 = W2[(8 * q + 2 * p + 1) * 32 + 16 * tile + c];
            sp2(x0, x1, th, tl);
            A1h[tile][p] = th; A1l[tile][p] = tl;
            const float y0 = W2[(16 * tile + c) * 32 + 8 * q + 2 * p];
            const float y1 = W2[(16 * tile + c) * 32 + 8 * q + 2 * p + 1];
            sp2(y0, y1, th, tl);
            A2h[tile][p] = th; A2l[tile][p] = tl;
        }
    }

    // LDS transpose bases (dword indices). Write pairs {2q,2q+1,8+2q,8+2q+1},
    // read pairs {4q..4q+3}. Pair stride 17 (pad) -> conflict-free-ish.
    int* const ldsw = lds + wv * 544 + 34 * q + c;
    int* const ldsr = lds + wv * 544 + 68 * q + c;
    const int idx16 = (lane ^ 16) << 2;
    const int idx32 = (lane ^ 32) << 2;

    const float* pe = eps + bidx;
    const float* ph = hs + bidx;
    float*       po = out + bidx;

    float gamma = 0.0f;
    float e_cur = pe[0];
    float h_cur = ph[0];

    for (int t = 0; t < T_STEPS; ++t) {
        const int tn = (t < T_STEPS - 1) ? t + 1 : t;
        const float e_nxt = pe[tn * B_TOT];
        const float h_nxt = ph[tn * B_TOT];

        // z1 on D-set h's; a1 = softplus, g1 = sigmoid
        float a1[8], g1[8];
#pragma unroll
        for (int i = 0; i < 8; ++i) {
            const float z = fmaf(e_cur, W1e[i], fmaf(gamma, W1g[i], b1D[i]));
            sp_sig(z, a1[i], g1[i]);
        }

        // ---- transpose a1 (D-set rows -> B-frag k-set) via LDS ----
        {
            int hp0, lp0, hp1, lp1, hp2, lp2, hp3, lp3;
            sp2(a1[0], a1[1], hp0, lp0);
            sp2(a1[2], a1[3], hp1, lp1);
            sp2(a1[4], a1[5], hp2, lp2);
            sp2(a1[6], a1[7], hp3, lp3);
            ldsw[0]   = hp0; ldsw[17]  = hp1; ldsw[136] = hp2; ldsw[153] = hp3;
            ldsw[272] = lp0; ldsw[289] = lp1; ldsw[408] = lp2; ldsw[425] = lp3;
        }
        __builtin_amdgcn_wave_barrier();
        __builtin_amdgcn_s_waitcnt(0xC07F);   // lgkmcnt(0)
        __builtin_amdgcn_wave_barrier();
        i32x4 bh, bl;
        bh[0] = ldsr[0];   bh[1] = ldsr[17];  bh[2] = ldsr[34];  bh[3] = ldsr[51];
        bl[0] = ldsr[272]; bl[1] = ldsr[289]; bl[2] = ldsr[306]; bl[3] = ldsr[323];

        // ---- GEMM1: z2^T (+b2 via acc init) ----
        const short8 Bh = as_s8(bh), Bl = as_s8(bl);
        f32x4 acc0 = {b2D[0], b2D[1], b2D[2], b2D[3]};
        f32x4 acc1 = {b2D[4], b2D[5], b2D[6], b2D[7]};
        acc0 = MFMA(as_s8(A1h[0]), Bh, acc0);
        acc1 = MFMA(as_s8(A1h[1]), Bh, acc1);
        acc0 = MFMA(as_s8(A1h[0]), Bl, acc0);
        acc1 = MFMA(as_s8(A1h[1]), Bl, acc1);
        acc0 = MFMA(as_s8(A1l[0]), Bh, acc0);
        acc1 = MFMA(as_s8(A1l[1]), Bh, acc1);
        acc0 = MFMA(as_s8(A1l[0]), Bl, acc0);
        acc1 = MFMA(as_s8(A1l[1]), Bl, acc1);

        // v2 = sigmoid(z2) * W3 (D-set layout)
        float v2[8];
#pragma unroll
        for (int i = 0; i < 4; ++i) v2[i]     = sigm(acc0[i]) * W3D[i];
#pragma unroll
        for (int i = 0; i < 4; ++i) v2[4 + i] = sigm(acc1[i]) * W3D[4 + i];

        // ---- transpose v2 via LDS (same region; in-order DS pipe) ----
        {
            int hp0, lp0, hp1, lp1, hp2, lp2, hp3, lp3;
            sp2(v2[0], v2[1], hp0, lp0);
            sp2(v2[2], v2[3], hp1, lp1);
            sp2(v2[4], v2[5], hp2, lp2);
            sp2(v2[6], v2[7], hp3, lp3);
            ldsw[0]   = hp0; ldsw[17]  = hp1; ldsw[136] = hp2; ldsw[153] = hp3;
            ldsw[272] = lp0; ldsw[289] = lp1; ldsw[408] = lp2; ldsw[425] = lp3;
        }
        __builtin_amdgcn_wave_barrier();
        __builtin_amdgcn_s_waitcnt(0xC07F);
        __builtin_amdgcn_wave_barrier();
        i32x4 vh, vl;
        vh[0] = ldsr[0];   vh[1] = ldsr[17];  vh[2] = ldsr[34];  vh[3] = ldsr[51];
        vl[0] = ldsr[272]; vl[1] = ldsr[289]; vl[2] = ldsr[306]; vl[3] = ldsr[323];

        // ---- GEMM2: s1^T ----
        const short8 Vh = as_s8(vh), Vl = as_s8(vl);
        f32x4 sA = {0.f, 0.f, 0.f, 0.f};
        f32x4 sB = {0.f, 0.f, 0.f, 0.f};
        sA = MFMA(as_s8(A2h[0]), Vh, sA);
        sB = MFMA(as_s8(A2h[1]), Vh, sB);
        sA = MFMA(as_s8(A2h[0]), Vl, sA);
        sB = MFMA(as_s8(A2h[1]), Vl, sB);
        sA = MFMA(as_s8(A2l[0]), Vh, sA);
        sB = MFMA(as_s8(A2l[1]), Vh, sB);
        sA = MFMA(as_s8(A2l[0]), Vl, sA);
        sB = MFMA(as_s8(A2l[1]), Vl, sB);

        // v1 = g1 .* s1; partial g = v1 @ W1^T
        float p0 = 0.f, p1 = 0.f;
#pragma unroll
        for (int i = 0; i < 4; ++i) {
            const float v = g1[i] * sA[i];
            p0 = fmaf(v, W1e[i], p0);
            p1 = fmaf(v, W1g[i], p1);
        }
#pragma unroll
        for (int i = 0; i < 4; ++i) {
            const float v = g1[4 + i] * sB[i];
            p0 = fmaf(v, W1e[4 + i], p0);
            p1 = fmaf(v, W1g[4 + i], p1);
        }

        // reduce over the 4 quad-lanes (xor16 + xor32)
        p0 += __int_as_float(__builtin_amdgcn_ds_bpermute(idx16, __float_as_int(p0)));
        p1 += __int_as_float(__builtin_amdgcn_ds_bpermute(idx16, __float_as_int(p1)));
        p0 += __int_as_float(__builtin_amdgcn_ds_bpermute(idx32, __float_as_int(p0)));
        p1 += __int_as_float(__builtin_amdgcn_ds_bpermute(idx32, __float_as_int(p1)));

        po[t * B_TOT] = p0;                // 4 lanes/batch store same value
        gamma = fmaf(h_cur, -p1, gamma);
        e_cur = e_nxt;
        h_cur = h_nxt;
    }
}

extern "C" void kernel_launch(void* const* d_in, const int* in_sizes, int n_in,
                              void* d_out, int out_size, void* d_ws, size_t ws_size,
                              hipStream_t stream) {
    const float* eps = (const float*)d_in[0];
    const float* hs  = (const float*)d_in[1];
    const float* W1  = (const float*)d_in[2];
    const float* b1  = (const float*)d_in[3];
    const float* W2  = (const float*)d_in[4];
    const float* b2  = (const float*)d_in[5];
    const float* W3  = (const float*)d_in[6];
    float* out = (float*)d_out;

    // 64 batches per 256-thread block (4 waves x 16) -> 256 blocks, 1 wave/SIMD
    dim3 grid(B_TOT / 64), block(256);
    hipLaunchKernelGGL(rnn_scan, grid, block, 0, stream,
                       eps, hs, W1, b1, W2, b2, W3, out);
}

// Round 4
// 545.276 us; speedup vs baseline: 2.2026x; 1.1014x over previous
//
#include <hip/hip_runtime.h>
#include <hip/hip_bf16.h>

// RNNCell scan: T=512, B=16384, H=32.
// 16 batches per wave (batch = MFMA column). Uniform layout: lane (q,c)
// owns h = 8q..8q+7 for ALL per-h vectors (z1/a1/g1/v2/s1/W1/W3/b1/b2).
// The MFMA A-fragments are row-permuted (h(m,t) = 8*(m>>2)+4t+(m&3)) so each
// GEMM's output emerges already in the NEXT operand's fragment order —
// zero LDS transposes. bf16 hi/lo split (4 MFMAs/tile, two 2-deep chains)
// gives fp32-quality products. Final 4-lane reduction via ds_bpermute.

#define T_STEPS 512
#define B_TOT   16384

typedef __attribute__((ext_vector_type(8))) short short8;
typedef __attribute__((ext_vector_type(4))) float f32x4;
typedef __attribute__((ext_vector_type(4))) int   i32x4;

__device__ __forceinline__ short8 as_s8(i32x4 v) {
    union { i32x4 i; short8 s; } u; u.i = v; return u.s;
}

// softplus(z) and sigmoid(z), sharing exp(-|z|)
__device__ __forceinline__ void sp_sig(float z, float& sp, float& sg) {
    const float az = fabsf(z);
    const float e  = __builtin_amdgcn_exp2f(az * -1.44269504088896340736f);
    const float op = 1.0f + e;
    const float r  = __builtin_amdgcn_rcpf(op);
    const float lg = __builtin_amdgcn_logf(op);        // log2(1+e)
    sp = fmaxf(z, 0.0f) + 0.69314718055994530942f * lg;
    sg = (z >= 0.0f) ? r : e * r;
}

__device__ __forceinline__ float sigm(float z) {
    const float az = fabsf(z);
    const float e  = __builtin_amdgcn_exp2f(az * -1.44269504088896340736f);
    const float r  = __builtin_amdgcn_rcpf(1.0f + e);
    return (z >= 0.0f) ? r : e * r;
}

// split (x0,x1) into packed bf16 hi-pair + exact-residual lo-pair
__device__ __forceinline__ void sp2(float x0, float x1, int& hi, int& lo) {
    unsigned u0 = __float_as_uint(x0), u1 = __float_as_uint(x1);
    unsigned r0 = (u0 + 0x8000u) & 0xffff0000u;
    unsigned r1 = (u1 + 0x8000u) & 0xffff0000u;
    hi = (int)(r1 | (r0 >> 16));
    float l0 = x0 - __uint_as_float(r0);
    float l1 = x1 - __uint_as_float(r1);
    lo = (int)((__float_as_uint(l1) & 0xffff0000u) | (__float_as_uint(l0) >> 16));
}

#define MFMA(A, B, C) __builtin_amdgcn_mfma_f32_16x16x32_bf16((A), (B), (C), 0, 0, 0)

__global__ __launch_bounds__(256, 1) void rnn_scan(
    const float* __restrict__ eps, const float* __restrict__ hs,
    const float* __restrict__ W1,  const float* __restrict__ b1,
    const float* __restrict__ W2,  const float* __restrict__ b2,
    const float* __restrict__ W3,  float* __restrict__ out)
{
    const int lane = threadIdx.x & 63;
    const int wv   = threadIdx.x >> 6;
    const int c    = lane & 15;          // batch column
    const int q    = lane >> 4;          // k-quad: this lane owns h = 8q..8q+7
    const int bidx = blockIdx.x * 64 + wv * 16 + c;

    // per-lane small weights in the uniform h = 8q+i order
    float W1e[8], W1g[8], b1D[8], b2D[8], W3D[8];
#pragma unroll
    for (int i = 0; i < 8; ++i) {
        const int h = 8 * q + i;
        W1e[i] = W1[h];       // W1[0][h]
        W1g[i] = W1[32 + h];  // W1[1][h]
        b1D[i] = b1[h];
        b2D[i] = b2[h];
        W3D[i] = W3[h];
    }

    // A fragments (hi/lo bf16 split). Row permutation: h(m,t)=8*(m>>2)+4t+(m&3)
    // so D-row set of lane (q,c) is exactly h = 8q+4t+reg.
    // GEMM1 (z2^T = W2^T@a1^T): A1[t][m=c][k=8q+j] = W2[8q+j][h(c,t)]
    // GEMM2 (s1^T = W2 @v2^T): A2[t][m=c][k=8q+j] = W2[h(c,t)][8q+j]
    i32x4 A1h[2], A1l[2], A2h[2], A2l[2];
#pragma unroll
    for (int t = 0; t < 2; ++t) {
        const int hc = 8 * (c >> 2) + 4 * t + (c & 3);
#pragma unroll
        for (int p = 0; p < 4; ++p) {
            int th, tl;
            const float x0 = W2[(8 * q + 2 * p) * 32 + hc];
            const float x1 = W2[(8 * q + 2 * p + 1) * 32 + hc];
            sp2(x0, x1, th, tl);
            A1h[t][p] = th; A1l[t][p] = tl;
            const float y0 = W2[hc * 32 + 8 * q + 2 * p];
            const float y1 = W2[hc * 32 + 8 * q + 2 * p + 1];
            sp2(y0, y1, th, tl);
            A2h[t][p] = th; A2l[t][p] = tl;
        }
    }

    const int idx16 = (lane ^ 16) << 2;
    const int idx32 = (lane ^ 32) << 2;

    const float* pe = eps + bidx;
    const float* ph = hs + bidx;
    float*       po = out + bidx;

    float gamma = 0.0f;
    float e_cur = pe[0];
    float h_cur = ph[0];

    for (int t = 0; t < T_STEPS; ++t) {
        const int tn = (t < T_STEPS - 1) ? t + 1 : t;
        const float e_nxt = pe[tn * B_TOT];
        const float h_nxt = ph[tn * B_TOT];

        // z1 for h = 8q..8q+7 (B-frag k-order); a1 = softplus, g1 = sigmoid
        float a1[8], g1[8];
#pragma unroll
        for (int i = 0; i < 8; ++i) {
            const float z = fmaf(e_cur, W1e[i], fmaf(gamma, W1g[i], b1D[i]));
            sp_sig(z, a1[i], g1[i]);
        }

        // pack a1 directly into the B fragment (pairs k = 8q+2p, 8q+2p+1)
        i32x4 bh, bl;
        {
            int th, tl;
            sp2(a1[0], a1[1], th, tl); bh[0] = th; bl[0] = tl;
            sp2(a1[2], a1[3], th, tl); bh[1] = th; bl[1] = tl;
            sp2(a1[4], a1[5], th, tl); bh[2] = th; bl[2] = tl;
            sp2(a1[6], a1[7], th, tl); bh[3] = th; bl[3] = tl;
        }

        // ---- GEMM1: z2 (two tiles, two 2-deep chains each) ----
        const short8 Bh = as_s8(bh), Bl = as_s8(bl);
        f32x4 zA0 = {b2D[0], b2D[1], b2D[2], b2D[3]};   // tile0: h=8q+reg
        f32x4 zA1 = {b2D[4], b2D[5], b2D[6], b2D[7]};   // tile1: h=8q+4+reg
        f32x4 zB0 = {0.f, 0.f, 0.f, 0.f};
        f32x4 zB1 = {0.f, 0.f, 0.f, 0.f};
        zA0 = MFMA(as_s8(A1h[0]), Bh, zA0);
        zA1 = MFMA(as_s8(A1h[1]), Bh, zA1);
        zB0 = MFMA(as_s8(A1h[0]), Bl, zB0);
        zB1 = MFMA(as_s8(A1h[1]), Bl, zB1);
        zA0 = MFMA(as_s8(A1l[0]), Bl, zA0);
        zA1 = MFMA(as_s8(A1l[1]), Bl, zA1);
        zB0 = MFMA(as_s8(A1l[0]), Bh, zB0);
        zB1 = MFMA(as_s8(A1l[1]), Bh, zB1);

        // v2 = sigmoid(z2) * W3, already in B-frag k-order (h = 8q+i)
        float v2[8];
#pragma unroll
        for (int i = 0; i < 4; ++i) v2[i]     = sigm(zA0[i] + zB0[i]) * W3D[i];
#pragma unroll
        for (int i = 0; i < 4; ++i) v2[4 + i] = sigm(zA1[i] + zB1[i]) * W3D[4 + i];

        // pack v2 into B fragment
        i32x4 vh, vl;
        {
            int th, tl;
            sp2(v2[0], v2[1], th, tl); vh[0] = th; vl[0] = tl;
            sp2(v2[2], v2[3], th, tl); vh[1] = th; vl[1] = tl;
            sp2(v2[4], v2[5], th, tl); vh[2] = th; vl[2] = tl;
            sp2(v2[6], v2[7], th, tl); vh[3] = th; vl[3] = tl;
        }

        // ---- GEMM2: s1 ----
        const short8 Vh = as_s8(vh), Vl = as_s8(vl);
        f32x4 sA0 = {0.f, 0.f, 0.f, 0.f};
        f32x4 sA1 = {0.f, 0.f, 0.f, 0.f};
        f32x4 sB0 = {0.f, 0.f, 0.f, 0.f};
        f32x4 sB1 = {0.f, 0.f, 0.f, 0.f};
        sA0 = MFMA(as_s8(A2h[0]), Vh, sA0);
        sA1 = MFMA(as_s8(A2h[1]), Vh, sA1);
        sB0 = MFMA(as_s8(A2h[0]), Vl, sB0);
        sB1 = MFMA(as_s8(A2h[1]), Vl, sB1);
        sA0 = MFMA(as_s8(A2l[0]), Vl, sA0);
        sA1 = MFMA(as_s8(A2l[1]), Vl, sA1);
        sB0 = MFMA(as_s8(A2l[0]), Vh, sB0);
        sB1 = MFMA(as_s8(A2l[1]), Vh, sB1);

        // v1 = g1 .* s1 (h = 8q+i order); partial g = v1 @ W1^T
        float p0 = 0.f, p1 = 0.f;
#pragma unroll
        for (int i = 0; i < 4; ++i) {
            const float v = g1[i] * (sA0[i] + sB0[i]);
            p0 = fmaf(v, W1e[i], p0);
            p1 = fmaf(v, W1g[i], p1);
        }
#pragma unroll
        for (int i = 0; i < 4; ++i) {
            const float v = g1[4 + i] * (sA1[i] + sB1[i]);
            p0 = fmaf(v, W1e[4 + i], p0);
            p1 = fmaf(v, W1g[4 + i], p1);
        }

        // reduce over the 4 lanes of this batch column (xor16 + xor32)
        p0 += __int_as_float(__builtin_amdgcn_ds_bpermute(idx16, __float_as_int(p0)));
        p1 += __int_as_float(__builtin_amdgcn_ds_bpermute(idx16, __float_as_int(p1)));
        p0 += __int_as_float(__builtin_amdgcn_ds_bpermute(idx32, __float_as_int(p0)));
        p1 += __int_as_float(__builtin_amdgcn_ds_bpermute(idx32, __float_as_int(p1)));

        po[t * B_TOT] = p0;                // 4 lanes/batch store same value
        gamma = fmaf(h_cur, -p1, gamma);
        e_cur = e_nxt;
        h_cur = h_nxt;
    }
}

extern "C" void kernel_launch(void* const* d_in, const int* in_sizes, int n_in,
                              void* d_out, int out_size, void* d_ws, size_t ws_size,
                              hipStream_t stream) {
    const float* eps = (const float*)d_in[0];
    const float* hs  = (const float*)d_in[1];
    const float* W1  = (const float*)d_in[2];
    const float* b1  = (const float*)d_in[3];
    const float* W2  = (const float*)d_in[4];
    const float* b2  = (const float*)d_in[5];
    const float* W3  = (const float*)d_in[6];
    float* out = (float*)d_out;

    // 64 batches per 256-thread block (4 waves x 16) -> 256 blocks, 1 wave/SIMD
    dim3 grid(B_TOT / 64), block(256);
    hipLaunchKernelGGL(rnn_scan, grid, block, 0, stream,
                       eps, hs, W1, b1, W2, b2, W3, out);
}

// Round 5
// 463.002 us; speedup vs baseline: 2.5940x; 1.1777x over previous
//
#include <hip/hip_runtime.h>
#include <hip/hip_bf16.h>

// RNNCell scan: T=512, B=16384, H=32.
// 16 batches per wave (batch = MFMA column); lane (q,c) owns h = 8q..8q+7 for
// all per-h vectors. MFMA A-fragments row-permuted (h(m,t)=8*(m>>2)+4t+(m&3))
// so each GEMM's output emerges in the next operand's fragment order — zero
// LDS transposes. Trunc-based bf16 hi/lo split (exact residual), 3 MFMAs per
// tile (drop lo*lo term, ~2^-16 rel). Select-free sigmoid/softplus:
// sigma = rcp(1+exp2(-z*log2e)) (overflow-safe), softplus = z - ln(sigma).

#define T_STEPS 512
#define B_TOT   16384

typedef __attribute__((ext_vector_type(8))) short short8;
typedef __attribute__((ext_vector_type(4))) float f32x4;
typedef __attribute__((ext_vector_type(4))) int   i32x4;

__device__ __forceinline__ short8 as_s8(i32x4 v) {
    union { i32x4 i; short8 s; } u; u.i = v; return u.s;
}

#define NLOG2E -1.44269504088896340736f
#define LN2     0.69314718055994530942f

// sigma(z) = 1/(1+e^-z), select-free, safe at +-inf overflow
__device__ __forceinline__ float sigm(float z) {
    const float t = __builtin_amdgcn_exp2f(z * NLOG2E);   // e^{-z}
    return __builtin_amdgcn_rcpf(1.0f + t);
}

// softplus + sigmoid sharing one exp: sp(z) = z - ln(sigma(z))
__device__ __forceinline__ void sp_sig(float z, float& sp, float& sg) {
    const float t = __builtin_amdgcn_exp2f(z * NLOG2E);
    const float r = __builtin_amdgcn_rcpf(1.0f + t);
    sg = r;
    sp = fmaf(-LN2, __builtin_amdgcn_logf(r), z);         // z - ln2*log2(r)
}

// exact trunc split: hi = trunc-bf16 pair, lo = exact residual (trunc-packed)
__device__ __forceinline__ void sp2t(float x0, float x1, int& hi, int& lo) {
    const unsigned h0 = __float_as_uint(x0) & 0xffff0000u;
    const unsigned h1 = __float_as_uint(x1) & 0xffff0000u;
    hi = (int)(h1 | (h0 >> 16));
    const float l0 = x0 - __uint_as_float(h0);
    const float l1 = x1 - __uint_as_float(h1);
    lo = (int)((__float_as_uint(l1) & 0xffff0000u) | (__float_as_uint(l0) >> 16));
}

#define MFMA(A, B, C) __builtin_amdgcn_mfma_f32_16x16x32_bf16((A), (B), (C), 0, 0, 0)

__global__ __launch_bounds__(256, 1) void rnn_scan(
    const float* __restrict__ eps, const float* __restrict__ hs,
    const float* __restrict__ W1,  const float* __restrict__ b1,
    const float* __restrict__ W2,  const float* __restrict__ b2,
    const float* __restrict__ W3,  float* __restrict__ out)
{
    const int lane = threadIdx.x & 63;
    const int wv   = threadIdx.x >> 6;
    const int c    = lane & 15;          // batch column
    const int q    = lane >> 4;          // k-quad: this lane owns h = 8q..8q+7
    const int bidx = blockIdx.x * 64 + wv * 16 + c;

    // per-lane small weights in the uniform h = 8q+i order
    float W1e[8], W1g[8], b1D[8], b2D[8], W3D[8];
#pragma unroll
    for (int i = 0; i < 8; ++i) {
        const int h = 8 * q + i;
        W1e[i] = W1[h];       // W1[0][h]
        W1g[i] = W1[32 + h];  // W1[1][h]
        b1D[i] = b1[h];
        b2D[i] = b2[h];
        W3D[i] = W3[h];
    }

    // A fragments (hi/lo trunc split). Row permutation h(m,t)=8*(m>>2)+4t+(m&3)
    // GEMM1 (z2^T = W2^T@a1^T): A1[t][m=c][k=8q+j] = W2[8q+j][h(c,t)]
    // GEMM2 (s1^T = W2 @v2^T): A2[t][m=c][k=8q+j] = W2[h(c,t)][8q+j]
    i32x4 A1h[2], A1l[2], A2h[2], A2l[2];
#pragma unroll
    for (int t = 0; t < 2; ++t) {
        const int hc = 8 * (c >> 2) + 4 * t + (c & 3);
#pragma unroll
        for (int p = 0; p < 4; ++p) {
            int th, tl;
            const float x0 = W2[(8 * q + 2 * p) * 32 + hc];
            const float x1 = W2[(8 * q + 2 * p + 1) * 32 + hc];
            sp2t(x0, x1, th, tl);
            A1h[t][p] = th; A1l[t][p] = tl;
            const float y0 = W2[hc * 32 + 8 * q + 2 * p];
            const float y1 = W2[hc * 32 + 8 * q + 2 * p + 1];
            sp2t(y0, y1, th, tl);
            A2h[t][p] = th; A2l[t][p] = tl;
        }
    }

    const int idx16 = (lane ^ 16) << 2;
    const int idx32 = (lane ^ 32) << 2;

    const float* pe = eps + bidx + B_TOT;   // prefetch cursor (t+1)
    const float* ph = hs  + bidx + B_TOT;
    float*       po = out + bidx;

    float gamma = 0.0f;
    float e_cur = eps[bidx];
    float h_cur = hs[bidx];

#define STEP_BODY(PF)                                                          \
    {                                                                          \
        float e_nxt = 0.f, h_nxt = 0.f;                                        \
        if (PF) { e_nxt = pe[0]; h_nxt = ph[0]; pe += B_TOT; ph += B_TOT; }    \
        /* z1 for h = 8q..8q+7; a1 = softplus, g1 = sigmoid */                 \
        float a1[8], g1[8];                                                    \
        _Pragma("unroll")                                                      \
        for (int i = 0; i < 8; ++i) {                                          \
            const float z = fmaf(e_cur, W1e[i], fmaf(gamma, W1g[i], b1D[i]));  \
            sp_sig(z, a1[i], g1[i]);                                           \
        }                                                                      \
        /* pack a1 into B fragment (hi/lo) */                                  \
        i32x4 bh, bl;                                                          \
        {                                                                      \
            int th, tl;                                                        \
            sp2t(a1[0], a1[1], th, tl); bh[0] = th; bl[0] = tl;                \
            sp2t(a1[2], a1[3], th, tl); bh[1] = th; bl[1] = tl;                \
            sp2t(a1[4], a1[5], th, tl); bh[2] = th; bl[2] = tl;                \
            sp2t(a1[6], a1[7], th, tl); bh[3] = th; bl[3] = tl;                \
        }                                                                      \
        /* GEMM1: z2 = (Ah+Al)Bh + Ah*Bl (+b2) */                              \
        const short8 Bh = as_s8(bh), Bl = as_s8(bl);                           \
        f32x4 zA0 = {b2D[0], b2D[1], b2D[2], b2D[3]};                          \
        f32x4 zA1 = {b2D[4], b2D[5], b2D[6], b2D[7]};                          \
        f32x4 zB0 = {0.f, 0.f, 0.f, 0.f};                                      \
        f32x4 zB1 = {0.f, 0.f, 0.f, 0.f};                                      \
        zA0 = MFMA(as_s8(A1h[0]), Bh, zA0);                                    \
        zA1 = MFMA(as_s8(A1h[1]), Bh, zA1);                                    \
        zB0 = MFMA(as_s8(A1h[0]), Bl, zB0);                                    \
        zB1 = MFMA(as_s8(A1h[1]), Bl, zB1);                                    \
        zA0 = MFMA(as_s8(A1l[0]), Bh, zA0);                                    \
        zA1 = MFMA(as_s8(A1l[1]), Bh, zA1);                                    \
        /* v2 = sigmoid(z2) * W3 */                                            \
        float v2[8];                                                           \
        _Pragma("unroll")                                                      \
        for (int i = 0; i < 4; ++i) v2[i]     = sigm(zA0[i] + zB0[i]) * W3D[i];\
        _Pragma("unroll")                                                      \
        for (int i = 0; i < 4; ++i) v2[4+i]   = sigm(zA1[i] + zB1[i]) * W3D[4+i];\
        /* pack v2 into B fragment */                                          \
        i32x4 vh, vl;                                                          \
        {                                                                      \
            int th, tl;                                                        \
            sp2t(v2[0], v2[1], th, tl); vh[0] = th; vl[0] = tl;                \
            sp2t(v2[2], v2[3], th, tl); vh[1] = th; vl[1] = tl;                \
            sp2t(v2[4], v2[5], th, tl); vh[2] = th; vl[2] = tl;                \
            sp2t(v2[6], v2[7], th, tl); vh[3] = th; vl[3] = tl;                \
        }                                                                      \
        /* GEMM2: s1 = (Ah+Al)Vh + Ah*Vl */                                    \
        const short8 Vh = as_s8(vh), Vl = as_s8(vl);                           \
        f32x4 sA0 = {0.f, 0.f, 0.f, 0.f};                                      \
        f32x4 sA1 = {0.f, 0.f, 0.f, 0.f};                                      \
        f32x4 sB0 = {0.f, 0.f, 0.f, 0.f};                                      \
        f32x4 sB1 = {0.f, 0.f, 0.f, 0.f};                                      \
        sA0 = MFMA(as_s8(A2h[0]), Vh, sA0);                                    \
        sA1 = MFMA(as_s8(A2h[1]), Vh, sA1);                                    \
        sB0 = MFMA(as_s8(A2h[0]), Vl, sB0);                                    \
        sB1 = MFMA(as_s8(A2h[1]), Vl, sB1);                                    \
        sA0 = MFMA(as_s8(A2l[0]), Vh, sA0);                                    \
        sA1 = MFMA(as_s8(A2l[1]), Vh, sA1);                                    \
        /* v1 = g1 .* s1; partial g = v1 @ W1^T */                             \
        float p0 = 0.f, p1 = 0.f;                                              \
        _Pragma("unroll")                                                      \
        for (int i = 0; i < 4; ++i) {                                          \
            const float v = g1[i] * (sA0[i] + sB0[i]);                         \
            p0 = fmaf(v, W1e[i], p0);                                          \
            p1 = fmaf(v, W1g[i], p1);                                          \
        }                                                                      \
        _Pragma("unroll")                                                      \
        for (int i = 0; i < 4; ++i) {                                          \
            const float v = g1[4 + i] * (sA1[i] + sB1[i]);                     \
            p0 = fmaf(v, W1e[4 + i], p0);                                      \
            p1 = fmaf(v, W1g[4 + i], p1);                                      \
        }                                                                      \
        /* reduce over the 4 lanes of this batch column */                     \
        p0 += __int_as_float(__builtin_amdgcn_ds_bpermute(idx16, __float_as_int(p0))); \
        p1 += __int_as_float(__builtin_amdgcn_ds_bpermute(idx16, __float_as_int(p1))); \
        p0 += __int_as_float(__builtin_amdgcn_ds_bpermute(idx32, __float_as_int(p0))); \
        p1 += __int_as_float(__builtin_amdgcn_ds_bpermute(idx32, __float_as_int(p1))); \
        po[0] = p0;  po += B_TOT;                                              \
        gamma = fmaf(h_cur, -p1, gamma);                                       \
        e_cur = e_nxt;                                                         \
        h_cur = h_nxt;                                                         \
    }

    for (int t = 0; t < T_STEPS - 1; ++t) STEP_BODY(1)
    STEP_BODY(0)
#undef STEP_BODY
}

extern "C" void kernel_launch(void* const* d_in, const int* in_sizes, int n_in,
                              void* d_out, int out_size, void* d_ws, size_t ws_size,
                              hipStream_t stream) {
    const float* eps = (const float*)d_in[0];
    const float* hs  = (const float*)d_in[1];
    const float* W1  = (const float*)d_in[2];
    const float* b1  = (const float*)d_in[3];
    const float* W2  = (const float*)d_in[4];
    const float* b2  = (const float*)d_in[5];
    const float* W3  = (const float*)d_in[6];
    float* out = (float*)d_out;

    // 64 batches per 256-thread block (4 waves x 16) -> 256 blocks, 1 wave/SIMD
    dim3 grid(B_TOT / 64), block(256);
    hipLaunchKernelGGL(rnn_scan, grid, block, 0, stream,
                       eps, hs, W1, b1, W2, b2, W3, out);
}